// Round 12
// baseline (233.914 us; speedup 1.0000x reference)
//
#include <hip/hip_runtime.h>
#include <hip/hip_bf16.h>

typedef int  i32x4 __attribute__((ext_vector_type(4)));

// ---------------------------------------------------------------------------
// Fused prep: blocks [0, M) quantize x rows (fp32 -> int8 per-row symmetric,
// rowsum folded to fp32); blocks [M, ...) pack weight int32 codes to int8.
// ---------------------------------------------------------------------------
__global__ __launch_bounds__(256) void prep_fused(const float* __restrict__ x,
                                                  const int* __restrict__ w,
                                                  int* __restrict__ xq,
                                                  int* __restrict__ wq,
                                                  float* __restrict__ rsum,
                                                  float* __restrict__ rscale,
                                                  int M, int K) {
    if ((int)blockIdx.x >= M) {
        const size_t i = (size_t)(blockIdx.x - M) * blockDim.x + threadIdx.x;
        const int4* src = reinterpret_cast<const int4*>(w) + i * 4;
        int4 a = src[0], b = src[1], c = src[2], d = src[3];
        int4 o;
        o.x = (a.x & 255) | ((a.y & 255) << 8) | ((a.z & 255) << 16) | ((a.w & 255) << 24);
        o.y = (b.x & 255) | ((b.y & 255) << 8) | ((b.z & 255) << 16) | ((b.w & 255) << 24);
        o.z = (c.x & 255) | ((c.y & 255) << 8) | ((c.z & 255) << 16) | ((c.w & 255) << 24);
        o.w = (d.x & 255) | ((d.y & 255) << 8) | ((d.z & 255) << 16) | ((d.w & 255) << 24);
        reinterpret_cast<int4*>(wq)[i] = o;
        return;
    }
    const int row = blockIdx.x;
    const float* xr = x + (size_t)row * K;
    __shared__ float xs[4096];
    float mx = 0.f;
    for (int c = threadIdx.x * 4; c < K; c += blockDim.x * 4) {
        float4 v = *reinterpret_cast<const float4*>(xr + c);
        *reinterpret_cast<float4*>(xs + c) = v;
        mx = fmaxf(mx, fmaxf(fmaxf(fabsf(v.x), fabsf(v.y)),
                             fmaxf(fabsf(v.z), fabsf(v.w))));
    }
    #pragma unroll
    for (int off = 32; off > 0; off >>= 1) mx = fmaxf(mx, __shfl_down(mx, off));
    __shared__ float wmax[4];
    __shared__ float s_sx, s_inv;
    const int lane = threadIdx.x & 63, wv = threadIdx.x >> 6;
    if (lane == 0) wmax[wv] = mx;
    __syncthreads();
    if (threadIdx.x == 0) {
        float m = fmaxf(fmaxf(wmax[0], wmax[1]), fmaxf(wmax[2], wmax[3]));
        m = fmaxf(m, 1e-20f);
        s_sx = m / 127.f; s_inv = 127.f / m;
    }
    __syncthreads();
    const float inv = s_inv;
    int qs = 0;
    for (int c = threadIdx.x * 4; c < K; c += blockDim.x * 4) {
        float4 v = *reinterpret_cast<const float4*>(xs + c);
        const int q0 = __float2int_rn(v.x * inv), q1 = __float2int_rn(v.y * inv);
        const int q2 = __float2int_rn(v.z * inv), q3 = __float2int_rn(v.w * inv);
        qs += q0 + q1 + q2 + q3;
        const unsigned p = (unsigned)(q0 & 255) | ((unsigned)(q1 & 255) << 8) |
                           ((unsigned)(q2 & 255) << 16) | ((unsigned)(q3 & 255) << 24);
        xq[((size_t)row * K + c) >> 2] = (int)p;
    }
    #pragma unroll
    for (int off = 32; off > 0; off >>= 1) qs += __shfl_down(qs, off);
    __shared__ int wqs[4];
    if (lane == 0) wqs[wv] = qs;
    __syncthreads();
    if (threadIdx.x == 0) {
        const int t = wqs[0] + wqs[1] + wqs[2] + wqs[3];
        rsum[row] = s_sx * (float)t;
        rscale[row] = s_sx;
    }
}

// ---------------------------------------------------------------------------
// 256x256 int8 GEMM, B direct global->regs (asm-ledgered), A ring-4 LDS.
// Per phase (K=64 slab s):
//   READ af[8] (8 ds_read_b128, slot s&3) | BLOAD bf(s+1) (4 asm
//   global_load_dwordx4) | AST A(s+3) (2 gload_lds, slot (s+3)&3) |
//   lgkmcnt(0)+SB | 32 MFMA (af, bf(s)) | vmcnt(2) | barrier.
// vmcnt ledger (induction): entering phase s outstanding = A(s+2)x2; issue
// B(s+1)x4 then A(s+3)x2 -> 8; vmcnt(2) proves A(s+2)+B(s+1), leaves
// A(s+3). B(s+1) lands under the 32-MFMA window. Prologue: AST 0,1,2 +
// BLOAD B(0) -> vmcnt(0) proves all. Write-safety: slot (s+3)&3 == (s-1)&3
// whose reads were lgkm(0)-proven before phase s-1's barrier. Tail: clamped
// stages/loads land in dead slots/buffers (checked ph60-63 explicitly).
// ALL VMEM ops are builtin-gload_lds or asm volatile -> exact vmcnt
// composition (R8's race was compiler-scheduled plain-IR B loads).
// bf buffers alternate by static phase parity (even uses X, odd uses Y).
// out[m,o] = sc[o]*(sx[m]*dot_i32[m,o] - zp[o]*rsum[m]) + bias[o]
// ---------------------------------------------------------------------------
__device__ __forceinline__ void async16(void* lds, const void* g) {
    __builtin_amdgcn_global_load_lds(
        (const __attribute__((address_space(1))) unsigned*)g,
        (__attribute__((address_space(3))) unsigned*)lds, 16, 0, 0);
}

__device__ __forceinline__ i32x4 gload16(const void* p) {
    i32x4 r;
    asm volatile("global_load_dwordx4 %0, %1, off"
                 : "=&v"(r) : "v"(p) : "memory");
    return r;
}

__global__ __launch_bounds__(512, 2) void qgemmbd(
    const char* __restrict__ A, const char* __restrict__ B,
    const float* __restrict__ rsum, const float* __restrict__ rscale,
    const float* __restrict__ scale, const float* __restrict__ zp,
    const float* __restrict__ bias, float* __restrict__ C,
    int M, int N, int K) {
    extern __shared__ char smem[];
    char* const AsB = smem;            // 4 x 16 KiB A ring slots

    const int tid  = threadIdx.x;
    const int lane = tid & 63;
    const int wid  = tid >> 6;
    const int wm = wid >> 2, wn = wid & 3;   // 2 x 4 waves, wave tile 128x64
    const int l15 = lane & 15;

    // bijective XCD swizzle (gridDim.x % 8 == 0)
    const int nbn = N >> 8;
    int wg = blockIdx.x;
    wg = (wg & 7) * (gridDim.x >> 3) + (wg >> 3);
    const int bm = wg / nbn, bn = wg % nbn;

    // A staging source (inverse-swizzled global address), 2 gloads/thread
    const int r0s = tid >> 2, sls = tid & 3;
    size_t a_src[2];
    int lds_off[2];
    #pragma unroll
    for (int j = 0; j < 2; ++j) {
        const int row = r0s + j * 128;
        const int sl  = sls ^ ((row >> 1) & 3);
        a_src[j] = ((size_t)(bm * 256 + row)) * K + sl * 16;
        lds_off[j] = (j * 512 + tid) * 16;
    }

    auto AST = [&](int u, int sl) {          // stage A slab u into ring slot sl
        const int kc = u * 64;
        char* const da = AsB + sl * 16384;
        #pragma unroll
        for (int j = 0; j < 2; ++j) async16(da + lds_off[j], A + a_src[j] + kc);
    };

    // B fragment base pointers: row = bn*256 + wn*64 + nf*16 + l15,
    // 16 B at k-slot (lane>>4). Lanes {r, r+16, r+32, r+48} cover one full
    // 64B line per row -> same 16-line footprint as a coalesced load.
    const char* bp[4];
    #pragma unroll
    for (int n = 0; n < 4; ++n)
        bp[n] = B + ((size_t)(bn * 256 + wn * 64 + n * 16 + l15)) * K
                  + ((lane >> 4) << 4);

    // af read constants (swizzled ds_read address)
    const int sw16 = (((lane >> 4) ^ ((lane >> 1) & 3)) << 4);
    const int a_ro = (wm * 128 + l15) * 64 + sw16;   // + mf*1024

    i32x4 acc[8][4] = {};
    i32x4 bfX[4], bfY[4];

    const int NS = K >> 6;     // 64 slabs

#define BLOAD(DST, U)                                                          \
    {                                                                          \
        _Pragma("unroll")                                                      \
        for (int n = 0; n < 4; ++n)                                            \
            DST[n] = gload16(bp[n] + ((size_t)(U) << 6));                      \
    }

#define PHASE(S, SL, BUSE, BNXT)                                               \
    {                                                                          \
        const char* _ha = AsB + (SL) * 16384;                                  \
        i32x4 af[8];                                                           \
        _Pragma("unroll")                                                      \
        for (int m = 0; m < 8; ++m)                                            \
            af[m] = *(const i32x4*)(_ha + a_ro + m * 1024);                    \
        int _u1 = (S) + 1; if (_u1 >= NS) _u1 = NS - 1;                        \
        BLOAD(BNXT, _u1)                                                       \
        int _u3 = (S) + 3; if (_u3 >= NS) _u3 = NS - 1;                        \
        AST(_u3, ((SL) + 3) & 3);                                              \
        asm volatile("s_waitcnt lgkmcnt(0)" ::: "memory");                     \
        __builtin_amdgcn_sched_barrier(0);                                     \
        __builtin_amdgcn_s_setprio(1);                                         \
        _Pragma("unroll")                                                      \
        for (int m = 0; m < 8; ++m)                                            \
            _Pragma("unroll")                                                  \
            for (int n = 0; n < 4; ++n)                                        \
                acc[m][n] = __builtin_amdgcn_mfma_i32_16x16x64_i8(             \
                    af[m], BUSE[n], acc[m][n], 0, 0, 0);                       \
        __builtin_amdgcn_s_setprio(0);                                         \
        __builtin_amdgcn_sched_barrier(0);                                     \
        asm volatile("s_waitcnt vmcnt(2)" ::: "memory");                       \
        asm volatile("s_barrier" ::: "memory");                                \
    }

    // ---- prologue: A slabs 0,1,2 staged; B(0) -> bfX; prove ALL ----
    AST(0, 0); AST(1, 1); AST(2, 2);
    BLOAD(bfX, 0)
    asm volatile("s_waitcnt vmcnt(0)" ::: "memory");
    asm volatile("s_barrier" ::: "memory");

    #pragma unroll 1
    for (int i = 0; i < NS / 4; ++i) {
        const int s = 4 * i;
        PHASE(s + 0, 0, bfX, bfY)
        PHASE(s + 1, 1, bfY, bfX)
        PHASE(s + 2, 2, bfX, bfY)
        PHASE(s + 3, 3, bfY, bfX)
    }
#undef PHASE
#undef BLOAD

    // ---- epilogue: dequant. D: col=lane&15, row=4*(lane>>4)+i ----
    float sc[4], zz[4], bb[4];
    #pragma unroll
    for (int n = 0; n < 4; ++n) {
        const int o = bn * 256 + wn * 64 + n * 16 + l15;
        sc[n] = scale[o]; zz[n] = zp[o]; bb[n] = bias[o];
    }
    const int hi4 = (lane >> 4) << 2;
    #pragma unroll
    for (int mf = 0; mf < 8; ++mf) {
        const int r0 = bm * 256 + wm * 128 + mf * 16 + hi4;
        float rs[4], sx[4];
        #pragma unroll
        for (int i = 0; i < 4; ++i) { rs[i] = rsum[r0 + i]; sx[i] = rscale[r0 + i]; }
        #pragma unroll
        for (int n = 0; n < 4; ++n) {
            const int o = bn * 256 + wn * 64 + n * 16 + l15;
            #pragma unroll
            for (int i = 0; i < 4; ++i)
                C[(size_t)(r0 + i) * N + o] =
                    sc[n] * (sx[i] * (float)acc[mf][n][i] - zz[n] * rs[i]) + bb[n];
        }
    }
}

// ---------------------------------------------------------------------------
extern "C" void kernel_launch(void* const* d_in, const int* in_sizes, int n_in,
                              void* d_out, int out_size, void* d_ws, size_t ws_size,
                              hipStream_t stream) {
    const float* x     = (const float*)d_in[0];
    const int*   w     = (const int*)d_in[1];
    const float* scale = (const float*)d_in[2];
    const float* zp    = (const float*)d_in[3];
    const float* bias  = (const float*)d_in[4];
    float* out = (float*)d_out;

    const int N = in_sizes[2];              // D_OUT = 4096
    const int K = in_sizes[1] / N;          // D_IN  = 4096
    const int M = in_sizes[0] / K;          // B*S   = 8192

    char*  xq  = (char*)d_ws;                                   // M*K bytes
    char*  wq  = (char*)d_ws + (size_t)M * K;                   // N*K bytes
    float* rs  = (float*)((char*)d_ws + (size_t)M * K + (size_t)N * K);
    float* rsc = rs + M;

    const int wblocks = (int)(((size_t)N * K / 16) / 256);      // 4096
    prep_fused<<<M + wblocks, 256, 0, stream>>>(x, w, (int*)xq, (int*)wq,
                                                rs, rsc, M, K);

    (void)hipFuncSetAttribute((const void*)qgemmbd,
                              hipFuncAttributeMaxDynamicSharedMemorySize, 65536);
    const int nwg = (M / 256) * (N / 256);   // 512, % 8 == 0
    qgemmbd<<<nwg, 512, 65536, stream>>>(xq, wq, rs, rsc, scale, zp, bias,
                                         out, M, N, K);
}

// Round 13
// 177.419 us; speedup vs baseline: 1.3184x; 1.3184x over previous
//
#include <hip/hip_runtime.h>
#include <hip/hip_bf16.h>

typedef int  i32x4 __attribute__((ext_vector_type(4)));

// ---------------------------------------------------------------------------
// Fused prep: blocks [0, M) quantize x rows (fp32 -> int8 per-row symmetric,
// rowsum folded to fp32); blocks [M, ...) pack weight int32 codes to int8.
// ---------------------------------------------------------------------------
__global__ __launch_bounds__(256) void prep_fused(const float* __restrict__ x,
                                                  const int* __restrict__ w,
                                                  int* __restrict__ xq,
                                                  int* __restrict__ wq,
                                                  float* __restrict__ rsum,
                                                  float* __restrict__ rscale,
                                                  int M, int K) {
    if ((int)blockIdx.x >= M) {
        const size_t i = (size_t)(blockIdx.x - M) * blockDim.x + threadIdx.x;
        const int4* src = reinterpret_cast<const int4*>(w) + i * 4;
        int4 a = src[0], b = src[1], c = src[2], d = src[3];
        int4 o;
        o.x = (a.x & 255) | ((a.y & 255) << 8) | ((a.z & 255) << 16) | ((a.w & 255) << 24);
        o.y = (b.x & 255) | ((b.y & 255) << 8) | ((b.z & 255) << 16) | ((b.w & 255) << 24);
        o.z = (c.x & 255) | ((c.y & 255) << 8) | ((c.z & 255) << 16) | ((c.w & 255) << 24);
        o.w = (d.x & 255) | ((d.y & 255) << 8) | ((d.z & 255) << 16) | ((d.w & 255) << 24);
        reinterpret_cast<int4*>(wq)[i] = o;
        return;
    }
    const int row = blockIdx.x;
    const float* xr = x + (size_t)row * K;
    __shared__ float xs[4096];
    float mx = 0.f;
    for (int c = threadIdx.x * 4; c < K; c += blockDim.x * 4) {
        float4 v = *reinterpret_cast<const float4*>(xr + c);
        *reinterpret_cast<float4*>(xs + c) = v;
        mx = fmaxf(mx, fmaxf(fmaxf(fabsf(v.x), fabsf(v.y)),
                             fmaxf(fabsf(v.z), fabsf(v.w))));
    }
    #pragma unroll
    for (int off = 32; off > 0; off >>= 1) mx = fmaxf(mx, __shfl_down(mx, off));
    __shared__ float wmax[4];
    __shared__ float s_sx, s_inv;
    const int lane = threadIdx.x & 63, wv = threadIdx.x >> 6;
    if (lane == 0) wmax[wv] = mx;
    __syncthreads();
    if (threadIdx.x == 0) {
        float m = fmaxf(fmaxf(wmax[0], wmax[1]), fmaxf(wmax[2], wmax[3]));
        m = fmaxf(m, 1e-20f);
        s_sx = m / 127.f; s_inv = 127.f / m;
    }
    __syncthreads();
    const float inv = s_inv;
    int qs = 0;
    for (int c = threadIdx.x * 4; c < K; c += blockDim.x * 4) {
        float4 v = *reinterpret_cast<const float4*>(xs + c);
        const int q0 = __float2int_rn(v.x * inv), q1 = __float2int_rn(v.y * inv);
        const int q2 = __float2int_rn(v.z * inv), q3 = __float2int_rn(v.w * inv);
        qs += q0 + q1 + q2 + q3;
        const unsigned p = (unsigned)(q0 & 255) | ((unsigned)(q1 & 255) << 8) |
                           ((unsigned)(q2 & 255) << 16) | ((unsigned)(q3 & 255) << 24);
        xq[((size_t)row * K + c) >> 2] = (int)p;
    }
    #pragma unroll
    for (int off = 32; off > 0; off >>= 1) qs += __shfl_down(qs, off);
    __shared__ int wqs[4];
    if (lane == 0) wqs[wv] = qs;
    __syncthreads();
    if (threadIdx.x == 0) {
        const int t = wqs[0] + wqs[1] + wqs[2] + wqs[3];
        rsum[row] = s_sx * (float)t;
        rscale[row] = s_sx;
    }
}

// ---------------------------------------------------------------------------
// 256x256 int8 GEMM, ring-4 LDS, ONE phase per K=64 slab -- cross-wave
// ledger byte-identical to the R11-passing kernel (same barriers, same
// vmcnt(4), same STAGE targets, same swizzle). NEW (wave-private only):
// grouped-lgkm interleave so the DS pipe serves reads UNDER the MFMA pipe:
//   issue bf[0..3],af[0..1] |SB| af[2..3] |SB| af[4..5] |SB| af[6..7] |SB|
//   STAGE(s+3) | lgkm(6)->MFMA m0,1 | lgkm(4)->m2,3 | lgkm(2)->m4,5 |
//   lgkm(0)->m6,7 | vm(4) | barrier.
// DS retires in-order per wave (R4-proven); gload_lds counts vmcnt not
// lgkm, so lgkm arithmetic is exact. sched_barrier(0) after each lgkm
// (rule #18) and between read groups (pins issue order for the counts).
// vm ledger (R11-proven): enter phase with 4 outstanding (slab s+2),
// STAGE -> 8, vm(4) proves slab s+2 before phase s+1 reads... (2-phase
// landing slack; prologue vm(8) proves slab 0, phase 0's vm(4) proves 1,2).
// out[m,o] = sc[o]*(sx[m]*dot_i32[m,o] - zp[o]*rsum[m]) + bias[o]
// ---------------------------------------------------------------------------
__device__ __forceinline__ void async16(void* lds, const void* g) {
    __builtin_amdgcn_global_load_lds(
        (const __attribute__((address_space(1))) unsigned*)g,
        (__attribute__((address_space(3))) unsigned*)lds, 16, 0, 0);
}

__global__ __launch_bounds__(512, 2) void qgemmgl(
    const char* __restrict__ A, const char* __restrict__ B,
    const float* __restrict__ rsum, const float* __restrict__ rscale,
    const float* __restrict__ scale, const float* __restrict__ zp,
    const float* __restrict__ bias, float* __restrict__ C,
    int M, int N, int K) {
    extern __shared__ char smem[];
    char* const AsB = smem;            // 4 x 16 KiB A ring slots
    char* const BsB = smem + 65536;    // 4 x 16 KiB B ring slots

    const int tid  = threadIdx.x;
    const int lane = tid & 63;
    const int wid  = tid >> 6;
    const int wm = wid >> 2, wn = wid & 3;   // 2 x 4 waves, wave tile 128x64
    const int l15 = lane & 15;

    // bijective XCD swizzle (gridDim.x % 8 == 0)
    const int nbn = N >> 8;
    int wg = blockIdx.x;
    wg = (wg & 7) * (gridDim.x >> 3) + (wg >> 3);
    const int bm = wg / nbn, bn = wg % nbn;

    // per-thread staging source offsets (inverse-swizzled global address)
    const int r0s = tid >> 2, sls = tid & 3;
    size_t a_src[2], b_src[2];
    int lds_off[2];
    #pragma unroll
    for (int j = 0; j < 2; ++j) {
        const int row = r0s + j * 128;
        const int sl  = sls ^ ((row >> 1) & 3);
        a_src[j] = ((size_t)(bm * 256 + row)) * K + sl * 16;
        b_src[j] = ((size_t)(bn * 256 + row)) * K + sl * 16;
        lds_off[j] = (j * 512 + tid) * 16;
    }

    // stage slab u (K-byte offset u*64) into ring slot sl: A + B, 4 gloads
    auto STAGE = [&](int u, int sl) {
        const int kc = u * 64;
        char* const da = AsB + sl * 16384;
        char* const db = BsB + sl * 16384;
        #pragma unroll
        for (int j = 0; j < 2; ++j) async16(da + lds_off[j], A + a_src[j] + kc);
        #pragma unroll
        for (int j = 0; j < 2; ++j) async16(db + lds_off[j], B + b_src[j] + kc);
    };

    // fragment-read constants (swizzled ds_read address)
    const int sw16 = (((lane >> 4) ^ ((lane >> 1) & 3)) << 4);
    const int a_ro = (wm * 128 + l15) * 64 + sw16;   // + mf*1024, mf 0..7
    const int b_ro = (wn * 64 + l15) * 64 + sw16;    // + nf*1024, nf 0..3

    i32x4 acc[8][4] = {};

    const int NS = K >> 6;     // 64 slabs

#define SB  __builtin_amdgcn_sched_barrier(0);
#define LG(N) asm volatile("s_waitcnt lgkmcnt(" #N ")" ::: "memory"); SB

#define MF2(M0, BF)                                                            \
    _Pragma("unroll")                                                          \
    for (int m = (M0); m < (M0) + 2; ++m)                                      \
        _Pragma("unroll")                                                      \
        for (int n = 0; n < 4; ++n)                                            \
            acc[m][n] = __builtin_amdgcn_mfma_i32_16x16x64_i8(                 \
                af[m], BF[n], acc[m][n], 0, 0, 0);

#define PHASE(S, SL)                                                           \
    {                                                                          \
        const char* _ha = AsB + (SL) * 16384;                                  \
        const char* _hb = BsB + (SL) * 16384;                                  \
        i32x4 af[8], bf[4];                                                    \
        /* group 1: bf0-3, af0, af1 */                                         \
        _Pragma("unroll")                                                      \
        for (int n = 0; n < 4; ++n)                                            \
            bf[n] = *(const i32x4*)(_hb + b_ro + n * 1024);                    \
        af[0] = *(const i32x4*)(_ha + a_ro + 0 * 1024);                        \
        af[1] = *(const i32x4*)(_ha + a_ro + 1 * 1024);                        \
        SB                                                                     \
        af[2] = *(const i32x4*)(_ha + a_ro + 2 * 1024);                        \
        af[3] = *(const i32x4*)(_ha + a_ro + 3 * 1024);                        \
        SB                                                                     \
        af[4] = *(const i32x4*)(_ha + a_ro + 4 * 1024);                        \
        af[5] = *(const i32x4*)(_ha + a_ro + 5 * 1024);                        \
        SB                                                                     \
        af[6] = *(const i32x4*)(_ha + a_ro + 6 * 1024);                        \
        af[7] = *(const i32x4*)(_ha + a_ro + 7 * 1024);                        \
        SB                                                                     \
        int _u = (S) + 3; if (_u >= NS) _u = NS - 1;                           \
        STAGE(_u, ((SL) + 3) & 3);                                             \
        SB                                                                     \
        __builtin_amdgcn_s_setprio(1);                                         \
        LG(6)  MF2(0, bf)                                                      \
        LG(4)  MF2(2, bf)                                                      \
        LG(2)  MF2(4, bf)                                                      \
        LG(0)  MF2(6, bf)                                                      \
        __builtin_amdgcn_s_setprio(0);                                         \
        SB                                                                     \
        asm volatile("s_waitcnt vmcnt(4)" ::: "memory");                       \
        asm volatile("s_barrier" ::: "memory");                                \
    }

    // ---- prologue: stage slabs 0,1,2; prove slab 0 (vmcnt 12 -> 8) ----
    STAGE(0, 0); STAGE(1, 1); STAGE(2, 2);
    asm volatile("s_waitcnt vmcnt(8)" ::: "memory");
    asm volatile("s_barrier" ::: "memory");

    #pragma unroll 1
    for (int i = 0; i < NS / 4; ++i) {
        const int s = 4 * i;
        PHASE(s + 0, 0)
        PHASE(s + 1, 1)
        PHASE(s + 2, 2)
        PHASE(s + 3, 3)
    }
#undef PHASE
#undef MF2
#undef LG
#undef SB

    // ---- epilogue: dequant. D: col=lane&15, row=4*(lane>>4)+i ----
    float sc[4], zz[4], bb[4];
    #pragma unroll
    for (int n = 0; n < 4; ++n) {
        const int o = bn * 256 + wn * 64 + n * 16 + l15;
        sc[n] = scale[o]; zz[n] = zp[o]; bb[n] = bias[o];
    }
    const int hi4 = (lane >> 4) << 2;
    #pragma unroll
    for (int mf = 0; mf < 8; ++mf) {
        const int r0 = bm * 256 + wm * 128 + mf * 16 + hi4;
        float rs[4], sx[4];
        #pragma unroll
        for (int i = 0; i < 4; ++i) { rs[i] = rsum[r0 + i]; sx[i] = rscale[r0 + i]; }
        #pragma unroll
        for (int n = 0; n < 4; ++n) {
            const int o = bn * 256 + wn * 64 + n * 16 + l15;
            #pragma unroll
            for (int i = 0; i < 4; ++i)
                C[(size_t)(r0 + i) * N + o] =
                    sc[n] * (sx[i] * (float)acc[mf][n][i] - zz[n] * rs[i]) + bb[n];
        }
    }
}

// ---------------------------------------------------------------------------
extern "C" void kernel_launch(void* const* d_in, const int* in_sizes, int n_in,
                              void* d_out, int out_size, void* d_ws, size_t ws_size,
                              hipStream_t stream) {
    const float* x     = (const float*)d_in[0];
    const int*   w     = (const int*)d_in[1];
    const float* scale = (const float*)d_in[2];
    const float* zp    = (const float*)d_in[3];
    const float* bias  = (const float*)d_in[4];
    float* out = (float*)d_out;

    const int N = in_sizes[2];              // D_OUT = 4096
    const int K = in_sizes[1] / N;          // D_IN  = 4096
    const int M = in_sizes[0] / K;          // B*S   = 8192

    char*  xq  = (char*)d_ws;                                   // M*K bytes
    char*  wq  = (char*)d_ws + (size_t)M * K;                   // N*K bytes
    float* rs  = (float*)((char*)d_ws + (size_t)M * K + (size_t)N * K);
    float* rsc = rs + M;

    const int wblocks = (int)(((size_t)N * K / 16) / 256);      // 4096
    prep_fused<<<M + wblocks, 256, 0, stream>>>(x, w, (int*)xq, (int*)wq,
                                                rs, rsc, M, K);

    (void)hipFuncSetAttribute((const void*)qgemmgl,
                              hipFuncAttributeMaxDynamicSharedMemorySize, 131072);
    const int nwg = (M / 256) * (N / 256);   // 512, % 8 == 0
    qgemmgl<<<nwg, 512, 131072, stream>>>(xq, wq, rs, rsc, scale, zp, bias,
                                          out, M, N, K);
}